// Round 1
// baseline (668.643 us; speedup 1.0000x reference)
//
#include <hip/hip_runtime.h>

#define BATCH 8
#define CIN 64
#define H 128
#define W 128
#define OCH 64
#define HW (H*W)
#define OFFCH 18

static __device__ __forceinline__ int iclamp(int v, int lo, int hi) {
    return v < lo ? lo : (v > hi ? hi : v);
}

// ---------------- Kernel A: offset-predicting conv (3x3, pad 1, no bias) ----------------
// offset[b, o, y, x] = sum_{c,ky,kx} x[b,c,y-1+ky,x-1+kx] * w[o,c,ky,kx]
__global__ __launch_bounds__(256) void offset_conv_kernel(
    const float* __restrict__ x, const float* __restrict__ w, float* __restrict__ off)
{
    int idx = blockIdx.x * 256 + threadIdx.x;   // total = BATCH*18*H*W
    int xx = idx & (W - 1);
    int y  = (idx >> 7) & (H - 1);
    int t  = idx >> 14;            // b*18 + o
    int o  = t % OFFCH;
    int b  = t / OFFCH;
    if (b >= BATCH) return;

    const float* xb = x + (size_t)b * CIN * HW;
    float acc = 0.f;
    for (int c = 0; c < CIN; ++c) {
        const float* xc = xb + c * HW;
        const float* wc = w + (o * CIN + c) * 9;
        #pragma unroll
        for (int ky = 0; ky < 3; ++ky) {
            int yy = y + ky - 1;
            if (yy < 0 || yy >= H) continue;
            #pragma unroll
            for (int kx = 0; kx < 3; ++kx) {
                int xv = xx + kx - 1;
                if (xv < 0 || xv >= W) continue;
                acc += wc[ky * 3 + kx] * xc[yy * W + xv];
            }
        }
    }
    off[idx] = acc;
}

// ---------------- Kernel T: transpose w_deform [oc][c][k] -> wt [k][c][oc] ----------------
__global__ __launch_bounds__(256) void transpose_w_kernel(
    const float* __restrict__ w, float* __restrict__ wt)
{
    int i = blockIdx.x * 256 + threadIdx.x;   // over OCH*CIN*9
    if (i >= OCH * CIN * 9) return;
    int k  = i % 9;
    int c  = (i / 9) % CIN;
    int oc = i / (9 * CIN);
    wt[(k * CIN + c) * OCH + oc] = w[i];
}

// ---------------- Kernel B: deformable conv ----------------
// One block: 64 pixels (half of one row) x all 64 output channels. 256 threads.
// Per tap k: stage bilinear samples val[c][pix] in LDS, then accumulate.
__global__ __launch_bounds__(256) void deform_conv_kernel(
    const float* __restrict__ x, const float* __restrict__ off,
    const float* __restrict__ wt, const float* __restrict__ bias,
    float* __restrict__ out)
{
    __shared__ float val[CIN][64];

    int bid = blockIdx.x;            // BATCH*H*2 = 2048
    int xh  = bid & 1;
    int y   = (bid >> 1) & (H - 1);
    int b   = bid >> 8;
    int t   = threadIdx.x;
    int pix = t & 63;
    int grp = t >> 6;                // 0..3
    int xx  = xh * 64 + pix;

    const float* xb   = x + (size_t)b * CIN * HW;
    const float* offb = off + (size_t)b * OFFCH * HW;
    int oc_base = __builtin_amdgcn_readfirstlane(grp * 16);

    float acc[16];
    #pragma unroll
    for (int j = 0; j < 16; ++j) acc[j] = bias[oc_base + j];

    for (int k = 0; k < 9; ++k) {
        int ky = k / 3, kx = k % 3;
        float offy = offb[((2 * k    ) * H + y) * W + xx];
        float offx = offb[((2 * k + 1) * H + y) * W + xx];
        float py = (float)(y  - 1 + ky) + offy;
        float px = (float)(xx - 1 + kx) + offx;
        float y0f = floorf(py), x0f = floorf(px);
        float fy = py - y0f, fx = px - x0f;
        int y0 = (int)y0f, x0 = (int)x0f;
        int y1 = y0 + 1,  x1 = x0 + 1;
        float m00 = (1.f - fy) * (1.f - fx);
        float m01 = (1.f - fy) * fx;
        float m10 = fy * (1.f - fx);
        float m11 = fy * fx;
        if (y0 < 0 || y0 >= H) { m00 = 0.f; m01 = 0.f; }
        if (y1 < 0 || y1 >= H) { m10 = 0.f; m11 = 0.f; }
        if (x0 < 0 || x0 >= W) { m00 = 0.f; m10 = 0.f; }
        if (x1 < 0 || x1 >= W) { m01 = 0.f; m11 = 0.f; }
        int y0c = iclamp(y0, 0, H - 1), y1c = iclamp(y1, 0, H - 1);
        int x0c = iclamp(x0, 0, W - 1), x1c = iclamp(x1, 0, W - 1);
        int i00 = y0c * W + x0c, i01 = y0c * W + x1c;
        int i10 = y1c * W + x0c, i11 = y1c * W + x1c;

        // ---- stage: this thread covers channels [grp*16, grp*16+16) for its pixel
        {
            const float* xc = xb + (size_t)(grp * 16) * HW;
            #pragma unroll
            for (int ci = 0; ci < 16; ++ci) {
                float v = m00 * xc[i00] + m01 * xc[i01]
                        + m10 * xc[i10] + m11 * xc[i11];
                val[grp * 16 + ci][pix] = v;
                xc += HW;
            }
        }
        __syncthreads();

        // ---- accumulate: 16 output channels for this pixel
        {
            const float* wk = wt + (size_t)(k * CIN) * OCH + oc_base;
            for (int c = 0; c < CIN; ++c) {
                float v = val[c][pix];
                #pragma unroll
                for (int j = 0; j < 16; ++j) acc[j] += wk[c * OCH + j] * v;
            }
        }
        __syncthreads();
    }

    size_t obase = ((size_t)b * OCH + oc_base) * HW + (size_t)y * W + xx;
    #pragma unroll
    for (int j = 0; j < 16; ++j) out[obase + (size_t)j * HW] = acc[j];
}

extern "C" void kernel_launch(void* const* d_in, const int* in_sizes, int n_in,
                              void* d_out, int out_size, void* d_ws, size_t ws_size,
                              hipStream_t stream) {
    const float* x     = (const float*)d_in[0];
    const float* w_off = (const float*)d_in[1];
    const float* w_def = (const float*)d_in[2];
    const float* b_def = (const float*)d_in[3];
    float* out = (float*)d_out;

    float* off = (float*)d_ws;                              // BATCH*18*H*W floats
    float* wt  = off + (size_t)BATCH * OFFCH * HW;          // OCH*CIN*9 floats

    int total_off = BATCH * OFFCH * HW;                     // 2,359,296
    offset_conv_kernel<<<total_off / 256, 256, 0, stream>>>(x, w_off, off);
    transpose_w_kernel<<<(OCH * CIN * 9 + 255) / 256, 256, 0, stream>>>(w_def, wt);
    deform_conv_kernel<<<BATCH * H * 2, 256, 0, stream>>>(x, off, wt, b_def, out);
}

// Round 2
// 305.247 us; speedup vs baseline: 2.1905x; 2.1905x over previous
//
#include <hip/hip_runtime.h>

#define BATCH 8
#define CIN 64
#define H 128
#define W 128
#define OCH 64
#define HW (H*W)
#define OFFCH 18
#define CH 8

static __device__ __forceinline__ int iclamp(int v, int lo, int hi) {
    return v < lo ? lo : (v > hi ? hi : v);
}

// ---------------- transpose w_offset [o][c][tap] -> wq [c][tap][o] ----------------
__global__ __launch_bounds__(256) void transpose_woff_kernel(
    const float* __restrict__ w, float* __restrict__ wq)
{
    int i = blockIdx.x * 256 + threadIdx.x;   // over 18*64*9 = 10368
    if (i >= OFFCH * CIN * 9) return;
    int tap = i % 9;
    int c   = (i / 9) % CIN;
    int o   = i / (9 * CIN);
    wq[(c * 9 + tap) * OFFCH + o] = w[i];
}

// ---------------- transpose w_deform [oc][c][tap] -> wt [tap][c][oc] ----------------
__global__ __launch_bounds__(256) void transpose_w_kernel(
    const float* __restrict__ w, float* __restrict__ wt)
{
    int i = blockIdx.x * 256 + threadIdx.x;   // over OCH*CIN*9
    if (i >= OCH * CIN * 9) return;
    int k  = i % 9;
    int c  = (i / 9) % CIN;
    int oc = i / (9 * CIN);
    wt[(k * CIN + c) * OCH + oc] = w[i];
}

// ---------------- offset conv v2: LDS-tiled, register-blocked ----------------
// Block = (b, row-pair). 256 threads = 64 pixel-pairs x 2 rows x 2 o-groups.
// Thread: 9 o x 2 pixels = 18 accumulators. Weights via wave-uniform s_load.
__global__ __launch_bounds__(256) void offset_conv_v2(
    const float* __restrict__ x, const float* __restrict__ wq, float* __restrict__ off)
{
    __shared__ float xs[CH][4][132];   // 8 ch x 4 rows (y0-1..y0+2) x 130 cols (x=-1..128), padded

    int bid   = blockIdx.x;            // b*64 + ypair
    int ypair = bid & 63;
    int b     = bid >> 6;
    int y0    = ypair * 2;
    int tid   = threadIdx.x;
    int pp    = tid & 63;              // pixel pair -> x0 = pp*2
    int row   = (tid >> 6) & 1;        // wave-uniform
    int o_base = __builtin_amdgcn_readfirstlane((tid >> 7) * 9);  // wave-uniform: 0 or 9
    int x0    = pp * 2;

    const float* xb = x + (size_t)b * CIN * HW;

    float acc[2][9];
    #pragma unroll
    for (int p = 0; p < 2; ++p)
        #pragma unroll
        for (int j = 0; j < 9; ++j) acc[p][j] = 0.f;

    for (int c0 = 0; c0 < CIN; c0 += CH) {
        __syncthreads();
        // ---- stage CH channels x 4 rows x 130 cols, float2-packed
        for (int e = tid; e < CH * 4 * 65; e += 256) {
            int cc  = e / (4 * 65);
            int rem = e % (4 * 65);
            int r   = rem / 65;
            int xi  = (rem % 65) * 2;  // LDS col; global col = xi-1, xi
            int yy  = y0 - 1 + r;
            float v0 = 0.f, v1 = 0.f;
            if (yy >= 0 && yy < H) {
                const float* xr = xb + (size_t)(c0 + cc) * HW + yy * W;
                int xg = xi - 1;
                if (xg >= 0 && xg < W)     v0 = xr[xg];
                if (xg + 1 < W)            v1 = xr[xg + 1];   // xg+1 >= 0 always
            }
            *(float2*)&xs[cc][r][xi] = make_float2(v0, v1);
        }
        __syncthreads();

        // ---- compute
        for (int cc = 0; cc < CH; ++cc) {
            const float* wc = wq + (size_t)((c0 + cc) * 9) * OFFCH + o_base;
            #pragma unroll
            for (int ky = 0; ky < 3; ++ky) {
                float2 va = *(const float2*)&xs[cc][row + ky][x0];
                float2 vb = *(const float2*)&xs[cc][row + ky][x0 + 2];
                float vals[4] = {va.x, va.y, vb.x, vb.y};
                #pragma unroll
                for (int kx = 0; kx < 3; ++kx) {
                    float wv[9];
                    #pragma unroll
                    for (int j = 0; j < 9; ++j) wv[j] = wc[(ky * 3 + kx) * OFFCH + j];
                    #pragma unroll
                    for (int p = 0; p < 2; ++p) {
                        float v = vals[kx + p];
                        #pragma unroll
                        for (int j = 0; j < 9; ++j) acc[p][j] += wv[j] * v;
                    }
                }
            }
        }
    }

    int y = y0 + row;
    size_t obase = ((size_t)b * OFFCH + o_base) * HW + (size_t)y * W + x0;
    #pragma unroll
    for (int j = 0; j < 9; ++j) {
        *(float2*)&off[obase + (size_t)j * HW] = make_float2(acc[0][j], acc[1][j]);
    }
}

// ---------------- Kernel B: deformable conv (unchanged from R1) ----------------
__global__ __launch_bounds__(256) void deform_conv_kernel(
    const float* __restrict__ x, const float* __restrict__ off,
    const float* __restrict__ wt, const float* __restrict__ bias,
    float* __restrict__ out)
{
    __shared__ float val[CIN][64];

    int bid = blockIdx.x;            // BATCH*H*2 = 2048
    int xh  = bid & 1;
    int y   = (bid >> 1) & (H - 1);
    int b   = bid >> 8;
    int t   = threadIdx.x;
    int pix = t & 63;
    int grp = t >> 6;                // 0..3
    int xx  = xh * 64 + pix;

    const float* xb   = x + (size_t)b * CIN * HW;
    const float* offb = off + (size_t)b * OFFCH * HW;
    int oc_base = __builtin_amdgcn_readfirstlane(grp * 16);

    float acc[16];
    #pragma unroll
    for (int j = 0; j < 16; ++j) acc[j] = bias[oc_base + j];

    for (int k = 0; k < 9; ++k) {
        int ky = k / 3, kx = k % 3;
        float offy = offb[((2 * k    ) * H + y) * W + xx];
        float offx = offb[((2 * k + 1) * H + y) * W + xx];
        float py = (float)(y  - 1 + ky) + offy;
        float px = (float)(xx - 1 + kx) + offx;
        float y0f = floorf(py), x0f = floorf(px);
        float fy = py - y0f, fx = px - x0f;
        int y0 = (int)y0f, x0 = (int)x0f;
        int y1 = y0 + 1,  x1 = x0 + 1;
        float m00 = (1.f - fy) * (1.f - fx);
        float m01 = (1.f - fy) * fx;
        float m10 = fy * (1.f - fx);
        float m11 = fy * fx;
        if (y0 < 0 || y0 >= H) { m00 = 0.f; m01 = 0.f; }
        if (y1 < 0 || y1 >= H) { m10 = 0.f; m11 = 0.f; }
        if (x0 < 0 || x0 >= W) { m00 = 0.f; m10 = 0.f; }
        if (x1 < 0 || x1 >= W) { m01 = 0.f; m11 = 0.f; }
        int y0c = iclamp(y0, 0, H - 1), y1c = iclamp(y1, 0, H - 1);
        int x0c = iclamp(x0, 0, W - 1), x1c = iclamp(x1, 0, W - 1);
        int i00 = y0c * W + x0c, i01 = y0c * W + x1c;
        int i10 = y1c * W + x0c, i11 = y1c * W + x1c;

        {
            const float* xc = xb + (size_t)(grp * 16) * HW;
            #pragma unroll
            for (int ci = 0; ci < 16; ++ci) {
                float v = m00 * xc[i00] + m01 * xc[i01]
                        + m10 * xc[i10] + m11 * xc[i11];
                val[grp * 16 + ci][pix] = v;
                xc += HW;
            }
        }
        __syncthreads();

        {
            const float* wk = wt + (size_t)(k * CIN) * OCH + oc_base;
            for (int c = 0; c < CIN; ++c) {
                float v = val[c][pix];
                #pragma unroll
                for (int j = 0; j < 16; ++j) acc[j] += wk[c * OCH + j] * v;
            }
        }
        __syncthreads();
    }

    size_t obase = ((size_t)b * OCH + oc_base) * HW + (size_t)y * W + xx;
    #pragma unroll
    for (int j = 0; j < 16; ++j) out[obase + (size_t)j * HW] = acc[j];
}

extern "C" void kernel_launch(void* const* d_in, const int* in_sizes, int n_in,
                              void* d_out, int out_size, void* d_ws, size_t ws_size,
                              hipStream_t stream) {
    const float* x     = (const float*)d_in[0];
    const float* w_off = (const float*)d_in[1];
    const float* w_def = (const float*)d_in[2];
    const float* b_def = (const float*)d_in[3];
    float* out = (float*)d_out;

    float* off = (float*)d_ws;                              // 2,359,296 floats
    float* wt  = off + (size_t)BATCH * OFFCH * HW;          // 36,864 floats
    float* wq  = wt + (size_t)OCH * CIN * 9;                // 10,368 floats

    transpose_woff_kernel<<<(OFFCH * CIN * 9 + 255) / 256, 256, 0, stream>>>(w_off, wq);
    transpose_w_kernel<<<(OCH * CIN * 9 + 255) / 256, 256, 0, stream>>>(w_def, wt);
    offset_conv_v2<<<BATCH * 64, 256, 0, stream>>>(x, wq, off);
    deform_conv_kernel<<<BATCH * H * 2, 256, 0, stream>>>(x, off, wt, b_def, out);
}

// Round 3
// 279.744 us; speedup vs baseline: 2.3902x; 1.0912x over previous
//
#include <hip/hip_runtime.h>

#define BATCH 8
#define CIN 64
#define H 128
#define W 128
#define OCH 64
#define HW (H*W)
#define OFFCH 18
#define CH 8

using bf16x8 = __attribute__((ext_vector_type(8))) __bf16;
using f32x4  = __attribute__((ext_vector_type(4))) float;

static __device__ __forceinline__ int iclamp(int v, int lo, int hi) {
    return v < lo ? lo : (v > hi ? hi : v);
}

// ---------------- transpose w_offset [o][c][tap] -> wq [c][tap][o] ----------------
__global__ __launch_bounds__(256) void transpose_woff_kernel(
    const float* __restrict__ w, float* __restrict__ wq)
{
    int i = blockIdx.x * 256 + threadIdx.x;   // over 18*64*9 = 10368
    if (i >= OFFCH * CIN * 9) return;
    int tap = i % 9;
    int c   = (i / 9) % CIN;
    int o   = i / (9 * CIN);
    wq[(c * 9 + tap) * OFFCH + o] = w[i];
}

// ---------------- prep w_deform into MFMA A-fragment order (bf16) ----------------
// wp[tap][cs][mt][lane][j] = w_deform[oc = mt*16 + (lane&15)][c = cs*32 + (lane>>4)*8 + j][tap]
__global__ __launch_bounds__(256) void prep_wfrag_kernel(
    const float* __restrict__ w, __bf16* __restrict__ wp)
{
    int i = blockIdx.x * 256 + threadIdx.x;   // over 9*2*4*64*8 = 36864
    if (i >= 9 * 2 * 4 * 64 * 8) return;
    int j    = i & 7;
    int lane = (i >> 3) & 63;
    int mt   = (i >> 9) & 3;
    int cs   = (i >> 11) & 1;
    int tap  = i >> 12;
    int oc = mt * 16 + (lane & 15);
    int c  = cs * 32 + (lane >> 4) * 8 + j;
    wp[i] = (__bf16)w[(oc * CIN + c) * 9 + tap];
}

// ---------------- offset conv v2: LDS-tiled, register-blocked (unchanged) ----------------
__global__ __launch_bounds__(256) void offset_conv_v2(
    const float* __restrict__ x, const float* __restrict__ wq, float* __restrict__ off)
{
    __shared__ float xs[CH][4][132];

    int bid   = blockIdx.x;            // b*64 + ypair
    int ypair = bid & 63;
    int b     = bid >> 6;
    int y0    = ypair * 2;
    int tid   = threadIdx.x;
    int pp    = tid & 63;
    int row   = (tid >> 6) & 1;
    int o_base = __builtin_amdgcn_readfirstlane((tid >> 7) * 9);
    int x0    = pp * 2;

    const float* xb = x + (size_t)b * CIN * HW;

    float acc[2][9];
    #pragma unroll
    for (int p = 0; p < 2; ++p)
        #pragma unroll
        for (int j = 0; j < 9; ++j) acc[p][j] = 0.f;

    for (int c0 = 0; c0 < CIN; c0 += CH) {
        __syncthreads();
        for (int e = tid; e < CH * 4 * 65; e += 256) {
            int cc  = e / (4 * 65);
            int rem = e % (4 * 65);
            int r   = rem / 65;
            int xi  = (rem % 65) * 2;
            int yy  = y0 - 1 + r;
            float v0 = 0.f, v1 = 0.f;
            if (yy >= 0 && yy < H) {
                const float* xr = xb + (size_t)(c0 + cc) * HW + yy * W;
                int xg = xi - 1;
                if (xg >= 0 && xg < W)     v0 = xr[xg];
                if (xg + 1 < W)            v1 = xr[xg + 1];
            }
            *(float2*)&xs[cc][r][xi] = make_float2(v0, v1);
        }
        __syncthreads();

        for (int cc = 0; cc < CH; ++cc) {
            const float* wc = wq + (size_t)((c0 + cc) * 9) * OFFCH + o_base;
            #pragma unroll
            for (int ky = 0; ky < 3; ++ky) {
                float2 va = *(const float2*)&xs[cc][row + ky][x0];
                float2 vb = *(const float2*)&xs[cc][row + ky][x0 + 2];
                float vals[4] = {va.x, va.y, vb.x, vb.y};
                #pragma unroll
                for (int kx = 0; kx < 3; ++kx) {
                    float wv[9];
                    #pragma unroll
                    for (int j = 0; j < 9; ++j) wv[j] = wc[(ky * 3 + kx) * OFFCH + j];
                    #pragma unroll
                    for (int p = 0; p < 2; ++p) {
                        float v = vals[kx + p];
                        #pragma unroll
                        for (int j = 0; j < 9; ++j) acc[p][j] += wv[j] * v;
                    }
                }
            }
        }
    }

    int y = y0 + row;
    size_t obase = ((size_t)b * OFFCH + o_base) * HW + (size_t)y * W + x0;
    #pragma unroll
    for (int j = 0; j < 9; ++j) {
        *(float2*)&off[obase + (size_t)j * HW] = make_float2(acc[0][j], acc[1][j]);
    }
}

// ---------------- deform conv via MFMA, register-direct gathered B-frags ----------------
// Block = (b, y): 1024 blocks, 4 waves. Wave w owns pixels [w*32, w*32+32) x all 64 oc.
// B-frag gather: lane l = pixel (l&15) of n-tile, channels 8*(l>>4)+j.
__global__ __launch_bounds__(256, 4) void deform_mfma_kernel(
    const float* __restrict__ x, const float* __restrict__ off,
    const bf16x8* __restrict__ wp, const float* __restrict__ bias,
    float* __restrict__ out)
{
    int bid  = blockIdx.x;           // 1024
    int b    = bid & 7;              // one batch per XCD (round-robin dispatch)
    int y    = bid >> 3;
    int tid  = threadIdx.x;
    int lane = tid & 63;
    int wave = tid >> 6;
    int l15  = lane & 15;
    int lk   = lane >> 4;
    int pixbase = wave * 32;

    const float* xb   = x + (size_t)b * CIN * HW;
    const float* offb = off + (size_t)b * OFFCH * HW + (size_t)y * W;

    f32x4 acc[4][2];
    #pragma unroll
    for (int mt = 0; mt < 4; ++mt)
        #pragma unroll
        for (int nt = 0; nt < 2; ++nt)
            acc[mt][nt] = (f32x4){0.f, 0.f, 0.f, 0.f};

    for (int tap = 0; tap < 9; ++tap) {
        int ky = tap / 3;
        int kx = tap - 3 * ky;

        // bilinear setup, one pixel per lane per n-tile
        float c00[2], c01[2], c10[2], c11[2];
        int   i00[2], i01[2], i10[2], i11[2];
        #pragma unroll
        for (int nt = 0; nt < 2; ++nt) {
            int p = pixbase + nt * 16 + l15;
            float offy = offb[(size_t)(2 * tap) * HW + p];
            float offx = offb[(size_t)(2 * tap + 1) * HW + p];
            float py = (float)(y - 1 + ky) + offy;
            float px = (float)(p - 1 + kx) + offx;
            float y0f = floorf(py), x0f = floorf(px);
            float fy = py - y0f, fx = px - x0f;
            int y0 = (int)y0f, x0 = (int)x0f;
            int y1 = y0 + 1, x1 = x0 + 1;
            float m00 = (1.f - fy) * (1.f - fx);
            float m01 = (1.f - fy) * fx;
            float m10 = fy * (1.f - fx);
            float m11 = fy * fx;
            if (y0 < 0 || y0 >= H) { m00 = 0.f; m01 = 0.f; }
            if (y1 < 0 || y1 >= H) { m10 = 0.f; m11 = 0.f; }
            if (x0 < 0 || x0 >= W) { m00 = 0.f; m10 = 0.f; }
            if (x1 < 0 || x1 >= W) { m01 = 0.f; m11 = 0.f; }
            int y0c = iclamp(y0, 0, H - 1), y1c = iclamp(y1, 0, H - 1);
            int x0c = iclamp(x0, 0, W - 1), x1c = iclamp(x1, 0, W - 1);
            c00[nt] = m00; c01[nt] = m01; c10[nt] = m10; c11[nt] = m11;
            i00[nt] = y0c * W + x0c; i01[nt] = y0c * W + x1c;
            i10[nt] = y1c * W + x0c; i11[nt] = y1c * W + x1c;
        }

        #pragma unroll
        for (int cs = 0; cs < 2; ++cs) {
            // A-frags: frag-ordered global load, 16B/lane coalesced
            bf16x8 afrag[4];
            const bf16x8* wf = wp + (size_t)((tap * 2 + cs) * 4) * 64 + lane;
            #pragma unroll
            for (int mt = 0; mt < 4; ++mt) afrag[mt] = wf[mt * 64];

            #pragma unroll
            for (int nt = 0; nt < 2; ++nt) {
                const float* xc = xb + (size_t)(cs * 32 + lk * 8) * HW;
                bf16x8 bfrag;
                #pragma unroll
                for (int j = 0; j < 8; ++j) {
                    float v = c00[nt] * xc[i00[nt]] + c01[nt] * xc[i01[nt]]
                            + c10[nt] * xc[i10[nt]] + c11[nt] * xc[i11[nt]];
                    bfrag[j] = (__bf16)v;
                    xc += HW;
                }
                #pragma unroll
                for (int mt = 0; mt < 4; ++mt)
                    acc[mt][nt] = __builtin_amdgcn_mfma_f32_16x16x32_bf16(
                        afrag[mt], bfrag, acc[mt][nt], 0, 0, 0);
            }
        }
    }

    // epilogue: D col = lane&15 (pixel), row = (lane>>4)*4 + r (oc within tile)
    #pragma unroll
    for (int mt = 0; mt < 4; ++mt) {
        #pragma unroll
        for (int nt = 0; nt < 2; ++nt) {
            int p = pixbase + nt * 16 + l15;
            #pragma unroll
            for (int r = 0; r < 4; ++r) {
                int oc = mt * 16 + lk * 4 + r;
                out[((size_t)b * OCH + oc) * HW + (size_t)y * W + p] = acc[mt][nt][r] + bias[oc];
            }
        }
    }
}

extern "C" void kernel_launch(void* const* d_in, const int* in_sizes, int n_in,
                              void* d_out, int out_size, void* d_ws, size_t ws_size,
                              hipStream_t stream) {
    const float* x     = (const float*)d_in[0];
    const float* w_off = (const float*)d_in[1];
    const float* w_def = (const float*)d_in[2];
    const float* b_def = (const float*)d_in[3];
    float* out = (float*)d_out;

    float*  off = (float*)d_ws;                             // 2,359,296 f32
    float*  wq  = off + (size_t)BATCH * OFFCH * HW;         // 10,368 f32
    __bf16* wp  = (__bf16*)(wq + OFFCH * CIN * 9);          // 36,864 bf16

    transpose_woff_kernel<<<(OFFCH * CIN * 9 + 255) / 256, 256, 0, stream>>>(w_off, wq);
    prep_wfrag_kernel<<<(9 * 2 * 4 * 64 * 8 + 255) / 256, 256, 0, stream>>>(w_def, wp);
    offset_conv_v2<<<BATCH * 64, 256, 0, stream>>>(x, wq, off);
    deform_mfma_kernel<<<BATCH * H, 256, 0, stream>>>(x, off, (const bf16x8*)wp, b_def, out);
}

// Round 4
// 115.656 us; speedup vs baseline: 5.7813x; 2.4188x over previous
//
#include <hip/hip_runtime.h>

#define BATCH 8
#define CIN 64
#define H 128
#define W 128
#define OCH 64
#define HW (H*W)
#define OFFCH 18

using f16x8 = __attribute__((ext_vector_type(8))) _Float16;
using f32x4 = __attribute__((ext_vector_type(4))) float;

static __device__ __forceinline__ int iclamp(int v, int lo, int hi) {
    return v < lo ? lo : (v > hi ? hi : v);
}
static __device__ __forceinline__ f16x8 splat8(_Float16 v) {
    return (f16x8){v, v, v, v, v, v, v, v};
}

// ---------------- transpose x [B][C][H][W] f32 -> xt [B][H][W][C] f16 ----------------
__global__ __launch_bounds__(256) void transpose_x_kernel(
    const float* __restrict__ x, _Float16* __restrict__ xt)
{
    __shared__ float ls[CIN][129];
    int bid = blockIdx.x;          // B*H = 1024
    int b = bid >> 7, y = bid & 127;
    int t = threadIdx.x;

    const float* xb = x + (size_t)b * CIN * HW + (size_t)y * W;
    #pragma unroll 4
    for (int i = 0; i < 32; ++i) {
        int c = i * 2 + (t >> 7);
        ls[c][t & 127] = xb[(size_t)c * HW + (t & 127)];
    }
    __syncthreads();

    _Float16* xo = xt + (size_t)(b * H + y) * W * CIN;
    #pragma unroll 4
    for (int i = 0; i < 16; ++i) {
        int px = i * 8 + (t >> 5);
        int c  = (t & 31) * 2;
        _Float16 a0 = (_Float16)ls[c][px];
        _Float16 a1 = (_Float16)ls[c + 1][px];
        union { _Float16 h[2]; unsigned int u; } pk;
        pk.h[0] = a0; pk.h[1] = a1;
        *(unsigned int*)&xo[(size_t)px * CIN + c] = pk.u;
    }
}

// ---------------- prep w_deform -> f16 MFMA A-frag order ----------------
// wdf[tap][cs][mt4][lane][j] = w_deform[oc=mt*16+(lane&15)][c=cs*32+(lane>>4)*8+j][tap]
__global__ __launch_bounds__(256) void prep_wdf_kernel(
    const float* __restrict__ w, _Float16* __restrict__ wdf)
{
    int i = blockIdx.x * 256 + threadIdx.x;   // 9*2*4*64*8 = 36864
    if (i >= 9 * 2 * 4 * 64 * 8) return;
    int j    = i & 7;
    int lane = (i >> 3) & 63;
    int mt   = (i >> 9) & 3;
    int cs   = (i >> 11) & 1;
    int tap  = i >> 12;
    int oc = mt * 16 + (lane & 15);
    int c  = cs * 32 + (lane >> 4) * 8 + j;
    wdf[i] = (_Float16)w[(oc * CIN + c) * 9 + tap];
}

// ---------------- prep w_offset -> f16 MFMA A-frag order (M padded 18->32) ----------------
// wof[tap][cs][mt2][lane][j]; oc = mt*16+(lane&15), zero for oc>=18
__global__ __launch_bounds__(256) void prep_wof_kernel(
    const float* __restrict__ w, _Float16* __restrict__ wof)
{
    int i = blockIdx.x * 256 + threadIdx.x;   // 9*2*2*64*8 = 18432
    if (i >= 9 * 2 * 2 * 64 * 8) return;
    int j    = i & 7;
    int lane = (i >> 3) & 63;
    int mt   = (i >> 9) & 1;
    int cs   = (i >> 10) & 1;
    int tap  = i >> 11;
    int oc = mt * 16 + (lane & 15);
    int c  = cs * 32 + (lane >> 4) * 8 + j;
    wof[i] = (oc < OFFCH) ? (_Float16)w[(oc * CIN + c) * 9 + tap] : (_Float16)0.f;
}

// ---------------- offset conv via MFMA over NHWC f16 ----------------
// Block=(b,y). 4 waves x 32 px. K = 9 taps x 64 ch, M = 32 (18 used), N = 32/wave.
__global__ __launch_bounds__(256, 4) void offset_mfma_kernel(
    const _Float16* __restrict__ xt, const f16x8* __restrict__ wof,
    float* __restrict__ off)
{
    int bid  = blockIdx.x;           // 1024
    int b    = bid & 7;
    int y    = bid >> 3;
    int tid  = threadIdx.x;
    int lane = tid & 63;
    int wave = tid >> 6;
    int l15  = lane & 15;
    int lk   = lane >> 4;
    int pixbase = wave * 32;

    const _Float16* xb = xt + (size_t)b * HW * CIN;

    f32x4 acc[2][2];
    #pragma unroll
    for (int mt = 0; mt < 2; ++mt)
        #pragma unroll
        for (int nt = 0; nt < 2; ++nt) acc[mt][nt] = (f32x4){0.f, 0.f, 0.f, 0.f};

    for (int tap = 0; tap < 9; ++tap) {
        int ky = tap / 3, kx = tap - 3 * ky;
        int yy = y - 1 + ky;
        #pragma unroll
        for (int cs = 0; cs < 2; ++cs) {
            f16x8 afrag[2];
            const f16x8* wf = wof + (size_t)((tap * 2 + cs) * 2) * 64 + lane;
            #pragma unroll
            for (int mt = 0; mt < 2; ++mt) afrag[mt] = wf[mt * 64];

            #pragma unroll
            for (int nt = 0; nt < 2; ++nt) {
                int p   = pixbase + nt * 16 + l15;
                int pos = p - 1 + kx;
                f16x8 bfrag = splat8((_Float16)0.f);
                if (yy >= 0 && yy < H && pos >= 0 && pos < W)
                    bfrag = *(const f16x8*)&xb[((size_t)yy * W + pos) * CIN + cs * 32 + lk * 8];
                #pragma unroll
                for (int mt = 0; mt < 2; ++mt)
                    acc[mt][nt] = __builtin_amdgcn_mfma_f32_16x16x32_f16(
                        afrag[mt], bfrag, acc[mt][nt], 0, 0, 0);
            }
        }
    }

    #pragma unroll
    for (int mt = 0; mt < 2; ++mt) {
        #pragma unroll
        for (int nt = 0; nt < 2; ++nt) {
            int p = pixbase + nt * 16 + l15;
            #pragma unroll
            for (int r = 0; r < 4; ++r) {
                int oc = mt * 16 + lk * 4 + r;
                if (oc < OFFCH)
                    off[((size_t)(b * OFFCH + oc) * H + y) * W + p] = acc[mt][nt][r];
            }
        }
    }
}

// ---------------- deformable conv via MFMA, NHWC f16 gathers ----------------
__global__ __launch_bounds__(256, 4) void deform_mfma_kernel(
    const _Float16* __restrict__ xt, const float* __restrict__ off,
    const f16x8* __restrict__ wdf, const float* __restrict__ bias,
    float* __restrict__ out)
{
    int bid  = blockIdx.x;           // 1024
    int b    = bid & 7;
    int y    = bid >> 3;
    int tid  = threadIdx.x;
    int lane = tid & 63;
    int wave = tid >> 6;
    int l15  = lane & 15;
    int lk   = lane >> 4;
    int pixbase = wave * 32;

    const _Float16* xb = xt + (size_t)b * HW * CIN;
    const float* offb  = off + (size_t)b * OFFCH * HW + (size_t)y * W;

    f32x4 acc[4][2];
    #pragma unroll
    for (int mt = 0; mt < 4; ++mt)
        #pragma unroll
        for (int nt = 0; nt < 2; ++nt) acc[mt][nt] = (f32x4){0.f, 0.f, 0.f, 0.f};

    for (int tap = 0; tap < 9; ++tap) {
        int ky = tap / 3, kx = tap - 3 * ky;

        _Float16 h00[2], h01[2], h10[2], h11[2];
        int i00[2], i01[2], i10[2], i11[2];
        #pragma unroll
        for (int nt = 0; nt < 2; ++nt) {
            int p = pixbase + nt * 16 + l15;
            float offy = offb[(size_t)(2 * tap) * HW + p];
            float offx = offb[(size_t)(2 * tap + 1) * HW + p];
            float py = (float)(y - 1 + ky) + offy;
            float px = (float)(p - 1 + kx) + offx;
            float y0f = floorf(py), x0f = floorf(px);
            float fy = py - y0f, fx = px - x0f;
            int y0 = (int)y0f, x0 = (int)x0f;
            int y1 = y0 + 1, x1 = x0 + 1;
            float m00 = (1.f - fy) * (1.f - fx);
            float m01 = (1.f - fy) * fx;
            float m10 = fy * (1.f - fx);
            float m11 = fy * fx;
            if (y0 < 0 || y0 >= H) { m00 = 0.f; m01 = 0.f; }
            if (y1 < 0 || y1 >= H) { m10 = 0.f; m11 = 0.f; }
            if (x0 < 0 || x0 >= W) { m00 = 0.f; m10 = 0.f; }
            if (x1 < 0 || x1 >= W) { m01 = 0.f; m11 = 0.f; }
            int y0c = iclamp(y0, 0, H - 1), y1c = iclamp(y1, 0, H - 1);
            int x0c = iclamp(x0, 0, W - 1), x1c = iclamp(x1, 0, W - 1);
            h00[nt] = (_Float16)m00; h01[nt] = (_Float16)m01;
            h10[nt] = (_Float16)m10; h11[nt] = (_Float16)m11;
            i00[nt] = (y0c * W + x0c) * CIN; i01[nt] = (y0c * W + x1c) * CIN;
            i10[nt] = (y1c * W + x0c) * CIN; i11[nt] = (y1c * W + x1c) * CIN;
        }

        #pragma unroll
        for (int cs = 0; cs < 2; ++cs) {
            f16x8 afrag[4];
            const f16x8* wf = wdf + (size_t)((tap * 2 + cs) * 4) * 64 + lane;
            #pragma unroll
            for (int mt = 0; mt < 4; ++mt) afrag[mt] = wf[mt * 64];

            int coff = cs * 32 + lk * 8;
            #pragma unroll
            for (int nt = 0; nt < 2; ++nt) {
                f16x8 g00 = *(const f16x8*)&xb[i00[nt] + coff];
                f16x8 g01 = *(const f16x8*)&xb[i01[nt] + coff];
                f16x8 g10 = *(const f16x8*)&xb[i10[nt] + coff];
                f16x8 g11 = *(const f16x8*)&xb[i11[nt] + coff];
                f16x8 bfrag = g00 * splat8(h00[nt]) + g01 * splat8(h01[nt])
                            + g10 * splat8(h10[nt]) + g11 * splat8(h11[nt]);
                #pragma unroll
                for (int mt = 0; mt < 4; ++mt)
                    acc[mt][nt] = __builtin_amdgcn_mfma_f32_16x16x32_f16(
                        afrag[mt], bfrag, acc[mt][nt], 0, 0, 0);
            }
        }
    }

    #pragma unroll
    for (int mt = 0; mt < 4; ++mt) {
        #pragma unroll
        for (int nt = 0; nt < 2; ++nt) {
            int p = pixbase + nt * 16 + l15;
            #pragma unroll
            for (int r = 0; r < 4; ++r) {
                int oc = mt * 16 + lk * 4 + r;
                out[((size_t)b * OCH + oc) * HW + (size_t)y * W + p] = acc[mt][nt][r] + bias[oc];
            }
        }
    }
}

extern "C" void kernel_launch(void* const* d_in, const int* in_sizes, int n_in,
                              void* d_out, int out_size, void* d_ws, size_t ws_size,
                              hipStream_t stream) {
    const float* x     = (const float*)d_in[0];
    const float* w_off = (const float*)d_in[1];
    const float* w_def = (const float*)d_in[2];
    const float* b_def = (const float*)d_in[3];
    float* out = (float*)d_out;

    float*    off = (float*)d_ws;                            // 2,359,296 f32 (9.4 MB)
    _Float16* xt  = (_Float16*)(off + (size_t)BATCH * OFFCH * HW); // 8.4M f16 (16.8 MB)
    _Float16* wdf = xt + (size_t)BATCH * HW * CIN;           // 36,864 f16
    _Float16* wof = wdf + 36864;                             // 18,432 f16

    transpose_x_kernel<<<BATCH * H, 256, 0, stream>>>(x, xt);
    prep_wdf_kernel<<<(36864 + 255) / 256, 256, 0, stream>>>(w_def, wdf);
    prep_wof_kernel<<<(18432 + 255) / 256, 256, 0, stream>>>(w_off, wof);
    offset_mfma_kernel<<<BATCH * H, 256, 0, stream>>>(xt, (const f16x8*)wof, off);
    deform_mfma_kernel<<<BATCH * H, 256, 0, stream>>>(xt, off, (const f16x8*)wdf, b_def, out);
}